// Round 14
// baseline (468.559 us; speedup 1.0000x reference)
//
#include <hip/hip_runtime.h>
#include <hip/hip_bf16.h>
#include <stdint.h>

// MultiHeadSelfAttention: B=2,H=16,S=2048,D=1024,DK=64. fp32 interface, bf16 MFMA internals.
// d_out = out[2,2048,1024] fp32 ++ attn[2,16,2048,2048] fp32.
//
// R14 = R13 with the OOB fix: attn_h no longer pre-offsets by qt (q is global).
//  - attn: wave-independent (no barriers/LDS), 8 waves x 16 q-rows, 4 waves/SIMD.
//  - XCD swizzle: 4 bh per XCD -> 2MB K/V working set fits 4MB L2.

typedef __attribute__((ext_vector_type(4))) float f32x4;
typedef __attribute__((ext_vector_type(8))) short s16x8;
typedef __attribute__((ext_vector_type(4))) unsigned int u32x4;
typedef __attribute__((ext_vector_type(2))) unsigned int u32x2;
typedef __attribute__((ext_vector_type(4))) unsigned short u16x4;

#define MFMA(a, b, c) __builtin_amdgcn_mfma_f32_16x16x32_bf16((a), (b), (c), 0, 0, 0)

#if __has_builtin(__builtin_amdgcn_exp2f)
#define EXP2(x) __builtin_amdgcn_exp2f(x)
#else
#define EXP2(x) exp2f(x)
#endif

__device__ __forceinline__ unsigned short f2bf(float f) {
    unsigned int u = __float_as_uint(f);
    unsigned int r = (u + 0x7FFFu + ((u >> 16) & 1u)) >> 16;
    return (unsigned short)r;
}
__device__ __forceinline__ unsigned int cvtpk_bf16(float lo, float hi) {
    unsigned int r;
    asm("v_cvt_pk_bf16_f32 %0, %1, %2" : "=v"(r) : "v"(lo), "v"(hi));
    return r;
}

// ---------------- Kernel 1: fp32 -> bf16 convert (x, wq, wk, wv, wo) ----------------
__global__ void convert_kernel(const float* __restrict__ x,
                               const float* __restrict__ wq, const float* __restrict__ wk,
                               const float* __restrict__ wv, const float* __restrict__ wo,
                               unsigned short* __restrict__ xb, unsigned short* __restrict__ wb) {
    size_t g = (size_t)blockIdx.x * blockDim.x + threadIdx.x;
    size_t i4 = g * 4;
    const float* src;
    unsigned short* dst;
    size_t off;
    if (i4 < 4194304) {            // x: 4096*1024
        src = x; dst = xb; off = i4;
    } else {
        size_t j = i4 - 4194304;
        int wsel = (int)(j >> 20); // each weight 1024*1024
        off = j & 1048575;
        src = (wsel == 0) ? wq : (wsel == 1) ? wk : (wsel == 2) ? wv : wo;
        dst = wb + ((size_t)wsel << 20);
    }
    float4 v = *(const float4*)(src + off);
    u16x4 o;
    o[0] = f2bf(v.x); o[1] = f2bf(v.y); o[2] = f2bf(v.z); o[3] = f2bf(v.w);
    *(u16x4*)(dst + off) = o;
}

// ---------------- Kernel 2/4: bt-GEMM, m97 structure ----------------
// mode 0 epilogue: Qs (scaled), Kb, and Vt with k-permuted columns (p = 8g+4ni+r per 32-block).
__global__ __launch_bounds__(256, 3) void gemm_kernel(
    const unsigned short* __restrict__ A, const unsigned short* __restrict__ B,
    const float* __restrict__ bias_q, const float* __restrict__ bias_k,
    const float* __restrict__ bias_v, int mode,
    unsigned short* __restrict__ Qs, unsigned short* __restrict__ Kb,
    unsigned short* __restrict__ Vt, float* __restrict__ outp) {
    const int t = threadIdx.x;
    const int lane = t & 63;
    const int wv4 = t >> 6;            // wave 0..3
    const int wr = wv4 >> 1, wc = wv4 & 1;
    const int rowbase = blockIdx.y * 128;
    const int colbase = blockIdx.x * 128;

    __shared__ __align__(16) unsigned short lA[128 * 64];
    __shared__ __align__(16) unsigned short lB[128 * 64];

    const int crow = lane >> 3;        // 0..7
    const int ccol = (lane & 7) * 8;   // 0..56

    f32x4 acc[4][4];
#pragma unroll
    for (int mi = 0; mi < 4; ++mi)
#pragma unroll
        for (int ni = 0; ni < 4; ++ni)
            acc[mi][ni] = (f32x4){0.f, 0.f, 0.f, 0.f};

    const int l15 = lane & 15;
    const int koff = (lane >> 4) * 8;
    const int ar = wr * 64 + l15;
    const int br = wc * 64 + l15;

    for (int kt = 0; kt < 16; ++kt) {
        const int kbase = kt * 64 + ccol;
#pragma unroll
        for (int i = 0; i < 4; ++i) {
            const int c = wv4 * 4 + i;
            const int r = c * 8 + crow;
            __builtin_amdgcn_global_load_lds(
                (const __attribute__((address_space(1))) void*)(A + (size_t)(rowbase + r) * 1024 + kbase),
                (__attribute__((address_space(3))) void*)&lA[c * 512], 16, 0, 0);
            __builtin_amdgcn_global_load_lds(
                (const __attribute__((address_space(1))) void*)(B + (size_t)(colbase + r) * 1024 + kbase),
                (__attribute__((address_space(3))) void*)&lB[c * 512], 16, 0, 0);
        }
        __syncthreads();
#pragma unroll
        for (int kk = 0; kk < 2; ++kk) {
            s16x8 af[4], bf[4];
#pragma unroll
            for (int mi = 0; mi < 4; ++mi)
                af[mi] = *(const s16x8*)&lA[(ar + mi * 16) * 64 + kk * 32 + koff];
#pragma unroll
            for (int ni = 0; ni < 4; ++ni)
                bf[ni] = *(const s16x8*)&lB[(br + ni * 16) * 64 + kk * 32 + koff];
#pragma unroll
            for (int mi = 0; mi < 4; ++mi)
#pragma unroll
                for (int ni = 0; ni < 4; ++ni)
                    acc[mi][ni] = MFMA(af[mi], bf[ni], acc[mi][ni]);
        }
        __syncthreads();
    }

    if (mode == 1) {
#pragma unroll
        for (int ni = 0; ni < 4; ++ni) {
            int n = colbase + wc * 64 + ni * 16 + l15;
            float bv = bias_q[n];
#pragma unroll
            for (int mi = 0; mi < 4; ++mi) {
#pragma unroll
                for (int reg = 0; reg < 4; ++reg) {
                    int m = rowbase + wr * 64 + mi * 16 + (lane >> 4) * 4 + reg;
                    outp[(size_t)m * 1024 + n] = acc[mi][ni][reg] + bv;
                }
            }
        }
    } else {
        const int proj = colbase >> 10;
        const float* bias = (proj == 0) ? bias_q : (proj == 1) ? bias_k : bias_v;
        const float scale = (proj == 0) ? 0.18033688011112042f : 1.0f;  // 0.125*log2(e)
#pragma unroll
        for (int ni = 0; ni < 4; ++ni) {
            int n = colbase + wc * 64 + ni * 16 + l15;
            int nn = n & 1023;
            int h = nn >> 6, d = nn & 63;
            float bv = bias[nn];
#pragma unroll
            for (int mi = 0; mi < 4; ++mi) {
                int m0 = rowbase + wr * 64 + mi * 16 + (lane >> 4) * 4;
                int b = m0 >> 11, s0 = m0 & 2047;
                if (proj == 2) {
                    u16x4 pk;
#pragma unroll
                    for (int reg = 0; reg < 4; ++reg)
                        pk[reg] = f2bf(acc[mi][ni][reg] + bv);
                    // k-permuted column within each 32-block: p = 8g + 4ni + r
                    int j0 = s0 & 31;
                    int pg = (j0 >> 2) & 3, pn = (j0 >> 4) & 1;
                    int pcol = (s0 & ~31) | (pg << 3) | (pn << 2);
                    *(u16x4*)&Vt[((size_t)(b * 16 + h) * 64 + d) * 2048 + pcol] = pk;
                } else {
                    unsigned short* dstp = (proj == 0) ? Qs : Kb;
#pragma unroll
                    for (int reg = 0; reg < 4; ++reg)
                        dstp[((size_t)(b * 16 + h) * 2048 + (s0 + reg)) * 64 + d] =
                            f2bf((acc[mi][ni][reg] + bv) * scale);
                }
            }
        }
    }
}

// ---------------- Kernel 3: attention -- wave-independent, barrier-free, no LDS -------------
// 512 threads = 8 waves; wave w owns q-rows qt*128 + w*16 + [0,16). Each wave:
// pass1 full-k denominators (2 shfl total), pass2 QK->exp->attn store->pack P->PV
// over both 32-k halves (permuted Vt). 4 waves/SIMD via launch_bounds(512,4).
__global__ __launch_bounds__(512, 4) void attn_kernel(
    const unsigned short* __restrict__ Qs, const unsigned short* __restrict__ Kb,
    const unsigned short* __restrict__ Vt, float* __restrict__ attn,
    unsigned short* __restrict__ ctx) {
    const int t = threadIdx.x;
    const int lane = t & 63;
    const int l15 = lane & 15;
    const int g = lane >> 4;
    const int g4 = g * 4, g8 = g * 8;
    const int w = t >> 6;  // wave 0..7

    // XCD swizzle: hw blocks i ≡ x (mod 8) -> work ids [64x, 64x+64) -> bh in [4x, 4x+4)
    const int wid = (blockIdx.x & 7) * 64 + (blockIdx.x >> 3);
    const int bh = wid >> 4;
    const int qt = wid & 15;
    const int b = bh >> 4, h = bh & 15;

    const unsigned short* Qh = Qs + (size_t)bh * (2048 * 64);
    const unsigned short* Kh = Kb + (size_t)bh * (2048 * 64);
    const unsigned short* Vh = Vt + (size_t)bh * (64 * 2048);
    float* attn_h = attn + (size_t)bh * (2048 * 2048);  // q is GLOBAL below (fix vs R13)

    const int qrow = qt * 128 + w * 16;  // wave's 16-row base (global)

    // Q fragments once (B-operand: col = q = l15, k = g8+e)
    s16x8 qf[2];
#pragma unroll
    for (int kk = 0; kk < 2; ++kk)
        qf[kk] = *(const s16x8*)&Qh[(size_t)(qrow + l15) * 64 + kk * 32 + g8];

    // ---- PASS 1: denominator for q = qrow + l15 (no barriers; 2 shfl total) ----
    float qsum = 0.f;
    for (int kt = 0; kt < 32; ++kt) {
        s16x8 kf[8];
#pragma unroll
        for (int ni = 0; ni < 4; ++ni)
#pragma unroll
            for (int kk = 0; kk < 2; ++kk)
                kf[ni * 2 + kk] =
                    *(const s16x8*)&Kh[(size_t)(kt * 64 + ni * 16 + l15) * 64 + kk * 32 + g8];
        f32x4 sacc[4];
#pragma unroll
        for (int ni = 0; ni < 4; ++ni) sacc[ni] = (f32x4){0.f, 0.f, 0.f, 0.f};
#pragma unroll
        for (int kk = 0; kk < 2; ++kk)
#pragma unroll
            for (int ni = 0; ni < 4; ++ni)
                sacc[ni] = MFMA(kf[ni * 2 + kk], qf[kk], sacc[ni]);
#pragma unroll
        for (int ni = 0; ni < 4; ++ni)
#pragma unroll
            for (int r = 0; r < 4; ++r) qsum += EXP2(sacc[ni][r]);
    }
    // butterfly over the 4 g-groups (same l15=q): all lanes end with the total
    qsum += __shfl_xor(qsum, 16);
    qsum += __shfl_xor(qsum, 32);
    const float rl = 1.0f / qsum;

    // ---- PASS 2: QK -> exp -> attn store -> pack P -> PV (all in-wave) ----
    f32x4 oacc[4];
#pragma unroll
    for (int db = 0; db < 4; ++db) oacc[db] = (f32x4){0.f, 0.f, 0.f, 0.f};

    for (int kt = 0; kt < 32; ++kt) {
        s16x8 kf[8];
#pragma unroll
        for (int ni = 0; ni < 4; ++ni)
#pragma unroll
            for (int kk = 0; kk < 2; ++kk)
                kf[ni * 2 + kk] =
                    *(const s16x8*)&Kh[(size_t)(kt * 64 + ni * 16 + l15) * 64 + kk * 32 + g8];
        s16x8 vf[8];  // vf[db*2+ks]: B-operand, col = d = db*16+l15, k slots match pf (permuted Vt)
#pragma unroll
        for (int db = 0; db < 4; ++db)
#pragma unroll
            for (int ks = 0; ks < 2; ++ks)
                vf[db * 2 + ks] =
                    *(const s16x8*)&Vh[(size_t)(db * 16 + l15) * 2048 + kt * 64 + ks * 32 + g8];
        f32x4 sacc[4];
#pragma unroll
        for (int ni = 0; ni < 4; ++ni) sacc[ni] = (f32x4){0.f, 0.f, 0.f, 0.f};
#pragma unroll
        for (int kk = 0; kk < 2; ++kk)
#pragma unroll
            for (int ni = 0; ni < 4; ++ni)
                sacc[ni] = MFMA(kf[ni * 2 + kk], qf[kk], sacc[ni]);

        // S^T fragment: lane holds q=l15 (col), k = ni*16 + g4 + r (row).
        s16x8 pf[2];
        const int q = qrow + l15;  // global row
#pragma unroll
        for (int ks = 0; ks < 2; ++ks) {
            u32x2 w0, w1;
#pragma unroll
            for (int nn = 0; nn < 2; ++nn) {
                const int ni = ks * 2 + nn;
                float p0 = EXP2(sacc[ni][0]) * rl;
                float p1 = EXP2(sacc[ni][1]) * rl;
                float p2 = EXP2(sacc[ni][2]) * rl;
                float p3 = EXP2(sacc[ni][3]) * rl;
                f32x4 pv = {p0, p1, p2, p3};
                *(f32x4*)&attn_h[(size_t)q * 2048 + kt * 64 + ni * 16 + g4] = pv;
                if (nn == 0) { w0[0] = cvtpk_bf16(p0, p1); w0[1] = cvtpk_bf16(p2, p3); }
                else         { w1[0] = cvtpk_bf16(p0, p1); w1[1] = cvtpk_bf16(p2, p3); }
            }
            u32x4 pkw = {w0[0], w0[1], w1[0], w1[1]};
            pf[ks] = *(const s16x8*)&pkw;
        }
#pragma unroll
        for (int db = 0; db < 4; ++db) {
            oacc[db] = MFMA(pf[0], vf[db * 2 + 0], oacc[db]);
            oacc[db] = MFMA(pf[1], vf[db * 2 + 1], oacc[db]);
        }
    }

    // ctx write: lane covers rows qrow + g4 + r, cols d = db*16 + l15
#pragma unroll
    for (int db = 0; db < 4; ++db) {
#pragma unroll
        for (int r = 0; r < 4; ++r) {
            int q = qrow + g4 + r;
            ctx[((size_t)(b * 2048 + q)) * 1024 + h * 64 + db * 16 + l15] = f2bf(oacc[db][r]);
        }
    }
}

// ---------------- launcher ----------------
extern "C" void kernel_launch(void* const* d_in, const int* in_sizes, int n_in,
                              void* d_out, int out_size, void* d_ws, size_t ws_size,
                              hipStream_t stream) {
    const float* x  = (const float*)d_in[0];
    const float* wq = (const float*)d_in[1];
    const float* bq = (const float*)d_in[2];
    const float* wk = (const float*)d_in[3];
    const float* bk = (const float*)d_in[4];
    const float* wv = (const float*)d_in[5];
    const float* bv = (const float*)d_in[6];
    const float* wo = (const float*)d_in[7];
    const float* bo = (const float*)d_in[8];

    char* ws = (char*)d_ws;
    unsigned short* xb  = (unsigned short*)(ws);                    // [4096][1024] bf16
    unsigned short* wb  = (unsigned short*)(ws + 8388608);          // [4][1024][1024] bf16
    unsigned short* Qsc = (unsigned short*)(ws + 16777216);         // [32][2048][64] bf16 (scaled)
    unsigned short* Kb  = (unsigned short*)(ws + 25165824);         // [32][2048][64] bf16
    unsigned short* Vt  = (unsigned short*)(ws + 33554432);         // [32][64][2048] bf16 (k-permuted)
    unsigned short* ctx = (unsigned short*)(ws + 41943040);         // [4096][1024] bf16

    float* out  = (float*)d_out;
    float* attn = out + 4194304;

    convert_kernel<<<8192, 256, 0, stream>>>(x, wq, wk, wv, wo, xb, wb);
    gemm_kernel<<<dim3(24, 32), 256, 0, stream>>>(xb, wb, bq, bk, bv, 0,
                                                  Qsc, Kb, Vt, nullptr);
    attn_kernel<<<512, 512, 0, stream>>>(Qsc, Kb, Vt, attn, ctx);
    gemm_kernel<<<dim3(8, 32), 256, 0, stream>>>(ctx, wb + 3 * 1048576, bo, bo, bo, 1,
                                                 nullptr, nullptr, nullptr, out);
}

// Round 16
// 336.382 us; speedup vs baseline: 1.3929x; 1.3929x over previous
//
#include <hip/hip_runtime.h>
#include <hip/hip_bf16.h>
#include <stdint.h>

// MultiHeadSelfAttention: B=2,H=16,S=2048,D=1024,DK=64. fp32 interface, bf16 MFMA internals.
// d_out = out[2,2048,1024] fp32 ++ attn[2,16,2048,2048] fp32.
//
// R16: attn q-split waves + in-wave LDS store transpose. Each wave owns 32 q x all 64 k:
//  - stores: S^T frag -> per-wave LDS scratch -> read transposed -> 4x256B segments/instr
//    (was 16x64B partial lines). Intra-wave only => ZERO barriers in the kernel.
//  - no lred/lO cross-wave exchanges (each wave owns its O rows; denom = 2 shfl).
// Q/K/V layouts identical to R10 (proven passing base).

typedef __attribute__((ext_vector_type(4))) float f32x4;
typedef __attribute__((ext_vector_type(8))) short s16x8;
typedef __attribute__((ext_vector_type(4))) unsigned int u32x4;
typedef __attribute__((ext_vector_type(4))) unsigned short u16x4;

#define MFMA(a, b, c) __builtin_amdgcn_mfma_f32_16x16x32_bf16((a), (b), (c), 0, 0, 0)

#if __has_builtin(__builtin_amdgcn_exp2f)
#define EXP2(x) __builtin_amdgcn_exp2f(x)
#else
#define EXP2(x) exp2f(x)
#endif

__device__ __forceinline__ unsigned short f2bf(float f) {
    unsigned int u = __float_as_uint(f);
    unsigned int r = (u + 0x7FFFu + ((u >> 16) & 1u)) >> 16;
    return (unsigned short)r;
}
__device__ __forceinline__ unsigned int cvtpk_bf16(float lo, float hi) {
    unsigned int r;
    asm("v_cvt_pk_bf16_f32 %0, %1, %2" : "=v"(r) : "v"(lo), "v"(hi));
    return r;
}

// ---------------- Kernel 1: fp32 -> bf16 convert (x, wq, wk, wv, wo) ----------------
__global__ void convert_kernel(const float* __restrict__ x,
                               const float* __restrict__ wq, const float* __restrict__ wk,
                               const float* __restrict__ wv, const float* __restrict__ wo,
                               unsigned short* __restrict__ xb, unsigned short* __restrict__ wb) {
    size_t g = (size_t)blockIdx.x * blockDim.x + threadIdx.x;
    size_t i4 = g * 4;
    const float* src;
    unsigned short* dst;
    size_t off;
    if (i4 < 4194304) {            // x: 4096*1024
        src = x; dst = xb; off = i4;
    } else {
        size_t j = i4 - 4194304;
        int wsel = (int)(j >> 20); // each weight 1024*1024
        off = j & 1048575;
        src = (wsel == 0) ? wq : (wsel == 1) ? wk : (wsel == 2) ? wv : wo;
        dst = wb + ((size_t)wsel << 20);
    }
    float4 v = *(const float4*)(src + off);
    u16x4 o;
    o[0] = f2bf(v.x); o[1] = f2bf(v.y); o[2] = f2bf(v.z); o[3] = f2bf(v.w);
    *(u16x4*)(dst + off) = o;
}

// ---------------- Kernel 2/4: bt-GEMM, m97 structure (R10 epilogue) ----------------
// mode 0 epilogue: Qs (scaled), Kb ([bh][s][64]), Vt ([bh][d][s] with k-permuted cols).
__global__ __launch_bounds__(256, 3) void gemm_kernel(
    const unsigned short* __restrict__ A, const unsigned short* __restrict__ B,
    const float* __restrict__ bias_q, const float* __restrict__ bias_k,
    const float* __restrict__ bias_v, int mode,
    unsigned short* __restrict__ Qs, unsigned short* __restrict__ Kb,
    unsigned short* __restrict__ Vt, float* __restrict__ outp) {
    const int t = threadIdx.x;
    const int lane = t & 63;
    const int wv4 = t >> 6;            // wave 0..3
    const int wr = wv4 >> 1, wc = wv4 & 1;
    const int rowbase = blockIdx.y * 128;
    const int colbase = blockIdx.x * 128;

    __shared__ __align__(16) unsigned short lA[128 * 64];
    __shared__ __align__(16) unsigned short lB[128 * 64];

    const int crow = lane >> 3;        // 0..7
    const int ccol = (lane & 7) * 8;   // 0..56

    f32x4 acc[4][4];
#pragma unroll
    for (int mi = 0; mi < 4; ++mi)
#pragma unroll
        for (int ni = 0; ni < 4; ++ni)
            acc[mi][ni] = (f32x4){0.f, 0.f, 0.f, 0.f};

    const int l15 = lane & 15;
    const int koff = (lane >> 4) * 8;
    const int ar = wr * 64 + l15;
    const int br = wc * 64 + l15;

    for (int kt = 0; kt < 16; ++kt) {
        const int kbase = kt * 64 + ccol;
#pragma unroll
        for (int i = 0; i < 4; ++i) {
            const int c = wv4 * 4 + i;
            const int r = c * 8 + crow;
            __builtin_amdgcn_global_load_lds(
                (const __attribute__((address_space(1))) void*)(A + (size_t)(rowbase + r) * 1024 + kbase),
                (__attribute__((address_space(3))) void*)&lA[c * 512], 16, 0, 0);
            __builtin_amdgcn_global_load_lds(
                (const __attribute__((address_space(1))) void*)(B + (size_t)(colbase + r) * 1024 + kbase),
                (__attribute__((address_space(3))) void*)&lB[c * 512], 16, 0, 0);
        }
        __syncthreads();
#pragma unroll
        for (int kk = 0; kk < 2; ++kk) {
            s16x8 af[4], bf[4];
#pragma unroll
            for (int mi = 0; mi < 4; ++mi)
                af[mi] = *(const s16x8*)&lA[(ar + mi * 16) * 64 + kk * 32 + koff];
#pragma unroll
            for (int ni = 0; ni < 4; ++ni)
                bf[ni] = *(const s16x8*)&lB[(br + ni * 16) * 64 + kk * 32 + koff];
#pragma unroll
            for (int mi = 0; mi < 4; ++mi)
#pragma unroll
                for (int ni = 0; ni < 4; ++ni)
                    acc[mi][ni] = MFMA(af[mi], bf[ni], acc[mi][ni]);
        }
        __syncthreads();
    }

    if (mode == 1) {
#pragma unroll
        for (int ni = 0; ni < 4; ++ni) {
            int n = colbase + wc * 64 + ni * 16 + l15;
            float bv = bias_q[n];
#pragma unroll
            for (int mi = 0; mi < 4; ++mi) {
#pragma unroll
                for (int reg = 0; reg < 4; ++reg) {
                    int m = rowbase + wr * 64 + mi * 16 + (lane >> 4) * 4 + reg;
                    outp[(size_t)m * 1024 + n] = acc[mi][ni][reg] + bv;
                }
            }
        }
    } else {
        const int proj = colbase >> 10;
        const float* bias = (proj == 0) ? bias_q : (proj == 1) ? bias_k : bias_v;
        const float scale = (proj == 0) ? 0.18033688011112042f : 1.0f;  // 0.125*log2(e)
#pragma unroll
        for (int ni = 0; ni < 4; ++ni) {
            int n = colbase + wc * 64 + ni * 16 + l15;
            int nn = n & 1023;
            int h = nn >> 6, d = nn & 63;
            float bv = bias[nn];
#pragma unroll
            for (int mi = 0; mi < 4; ++mi) {
                int m0 = rowbase + wr * 64 + mi * 16 + (lane >> 4) * 4;
                int b = m0 >> 11, s0 = m0 & 2047;
                if (proj == 2) {
                    u16x4 pk;
#pragma unroll
                    for (int reg = 0; reg < 4; ++reg)
                        pk[reg] = f2bf(acc[mi][ni][reg] + bv);
                    // k-permuted column within each 32-block: p = 8g + 4ni + r
                    int j0 = s0 & 31;
                    int pg = (j0 >> 2) & 3, pn = (j0 >> 4) & 1;
                    int pcol = (s0 & ~31) | (pg << 3) | (pn << 2);
                    *(u16x4*)&Vt[((size_t)(b * 16 + h) * 64 + d) * 2048 + pcol] = pk;
                } else {
                    unsigned short* dstp = (proj == 0) ? Qs : Kb;
#pragma unroll
                    for (int reg = 0; reg < 4; ++reg)
                        dstp[((size_t)(b * 16 + h) * 2048 + (s0 + reg)) * 64 + d] =
                            f2bf((acc[mi][ni][reg] + bv) * scale);
                }
            }
        }
    }
}

// ---------------- Kernel 3: attention -- q-split waves, barrier-free, LDS store transpose ----
// 4 waves; wave w owns q-rows [w*32, w*32+32) x ALL 64 k per kt.
__global__ __launch_bounds__(256, 2) void attn_kernel(
    const unsigned short* __restrict__ Qs, const unsigned short* __restrict__ Kb,
    const unsigned short* __restrict__ Vt, float* __restrict__ attn,
    unsigned short* __restrict__ ctx) {
    const int t = threadIdx.x;
    const int lane = t & 63;
    const int l15 = lane & 15;
    const int g = lane >> 4;
    const int g4 = g * 4, g8 = g * 8;
    const int w = t >> 6;
    const int qt = blockIdx.x;
    const int bh = blockIdx.y;
    const int b = bh >> 4, h = bh & 15;

    const unsigned short* Qh = Qs + (size_t)bh * (2048 * 64);
    const unsigned short* Kh = Kb + (size_t)bh * (2048 * 64);
    const unsigned short* Vh = Vt + (size_t)bh * (64 * 2048);
    float* attn_h = attn + (size_t)bh * (2048 * 2048) + (size_t)(qt * 128) * 2048;

    __shared__ float sc[4][32 * 68];  // per-wave transpose scratch (34.8 KB)

    const int qbase = w * 32;

    // Q fragments (B-operand): mi in {0,1}
    s16x8 qf[4];
#pragma unroll
    for (int mi = 0; mi < 2; ++mi)
#pragma unroll
        for (int kk = 0; kk < 2; ++kk)
            qf[mi * 2 + kk] = *(const s16x8*)&Qh[(size_t)(qt * 128 + qbase + mi * 16 + l15) * 64 +
                                                kk * 32 + g8];

    // ---- PASS 1: denominators (no barriers, no LDS, 2 shfl) ----
    float qsum[2] = {0.f, 0.f};
    for (int kt = 0; kt < 32; ++kt) {
        s16x8 kf[8];
#pragma unroll
        for (int ni = 0; ni < 4; ++ni)
#pragma unroll
            for (int kk = 0; kk < 2; ++kk)
                kf[ni * 2 + kk] =
                    *(const s16x8*)&Kh[(size_t)(kt * 64 + ni * 16 + l15) * 64 + kk * 32 + g8];
        f32x4 sacc[2][4];
#pragma unroll
        for (int mi = 0; mi < 2; ++mi)
#pragma unroll
            for (int ni = 0; ni < 4; ++ni) sacc[mi][ni] = (f32x4){0.f, 0.f, 0.f, 0.f};
#pragma unroll
        for (int kk = 0; kk < 2; ++kk)
#pragma unroll
            for (int mi = 0; mi < 2; ++mi)
#pragma unroll
                for (int ni = 0; ni < 4; ++ni)
                    sacc[mi][ni] = MFMA(kf[ni * 2 + kk], qf[mi * 2 + kk], sacc[mi][ni]);
#pragma unroll
        for (int mi = 0; mi < 2; ++mi) {
            float e = 0.f;
#pragma unroll
            for (int ni = 0; ni < 4; ++ni)
#pragma unroll
                for (int r = 0; r < 4; ++r) e += EXP2(sacc[mi][ni][r]);
            qsum[mi] += e;
        }
    }
    float rl[2];
#pragma unroll
    for (int mi = 0; mi < 2; ++mi) {
        float v = qsum[mi];
        v += __shfl_xor(v, 16);
        v += __shfl_xor(v, 32);
        rl[mi] = 1.0f / v;
    }

    // ---- PASS 2: QK -> exp -> LDS transpose -> coalesced stores -> PV ----
    f32x4 oacc[2][4];
#pragma unroll
    for (int mi = 0; mi < 2; ++mi)
#pragma unroll
        for (int db = 0; db < 4; ++db) oacc[mi][db] = (f32x4){0.f, 0.f, 0.f, 0.f};

    for (int kt = 0; kt < 32; ++kt) {
        s16x8 kf[8];
#pragma unroll
        for (int ni = 0; ni < 4; ++ni)
#pragma unroll
            for (int kk = 0; kk < 2; ++kk)
                kf[ni * 2 + kk] =
                    *(const s16x8*)&Kh[(size_t)(kt * 64 + ni * 16 + l15) * 64 + kk * 32 + g8];
        s16x8 vf[8];  // [db][ks] permuted-Vt B-operand fragments
#pragma unroll
        for (int db = 0; db < 4; ++db)
#pragma unroll
            for (int ks = 0; ks < 2; ++ks)
                vf[db * 2 + ks] =
                    *(const s16x8*)&Vh[(size_t)(db * 16 + l15) * 2048 + kt * 64 + ks * 32 + g8];
        f32x4 sacc[2][4];
#pragma unroll
        for (int mi = 0; mi < 2; ++mi)
#pragma unroll
            for (int ni = 0; ni < 4; ++ni) sacc[mi][ni] = (f32x4){0.f, 0.f, 0.f, 0.f};
#pragma unroll
        for (int kk = 0; kk < 2; ++kk)
#pragma unroll
            for (int mi = 0; mi < 2; ++mi)
#pragma unroll
                for (int ni = 0; ni < 4; ++ni)
                    sacc[mi][ni] = MFMA(kf[ni * 2 + kk], qf[mi * 2 + kk], sacc[mi][ni]);

        // exp + LDS write (S^T frag: q = mi*16+l15, k = ni*16+g4+r) + pf pack
        s16x8 pf0, pf1, pf2, pf3;  // [mi=0][ks=0,1], [mi=1][ks=0,1]
#pragma unroll
        for (int mi = 0; mi < 2; ++mi) {
            float p[16];
#pragma unroll
            for (int ni = 0; ni < 4; ++ni) {
#pragma unroll
                for (int r = 0; r < 4; ++r) p[ni * 4 + r] = EXP2(sacc[mi][ni][r]) * rl[mi];
                f32x4 pv = {p[ni * 4 + 0], p[ni * 4 + 1], p[ni * 4 + 2], p[ni * 4 + 3]};
                *(f32x4*)&sc[w][(mi * 16 + l15) * 68 + ni * 16 + g4] = pv;
            }
            u32x4 w0, w1;
            w0[0] = cvtpk_bf16(p[0], p[1]);   w0[1] = cvtpk_bf16(p[2], p[3]);
            w0[2] = cvtpk_bf16(p[4], p[5]);   w0[3] = cvtpk_bf16(p[6], p[7]);
            w1[0] = cvtpk_bf16(p[8], p[9]);   w1[1] = cvtpk_bf16(p[10], p[11]);
            w1[2] = cvtpk_bf16(p[12], p[13]); w1[3] = cvtpk_bf16(p[14], p[15]);
            if (mi == 0) { pf0 = *(const s16x8*)&w0; pf1 = *(const s16x8*)&w1; }
            else         { pf2 = *(const s16x8*)&w0; pf3 = *(const s16x8*)&w1; }
        }

        // transposed coalesced stores: 8 instrs, each 4 rows x 256B contiguous
#pragma unroll
        for (int i = 0; i < 8; ++i) {
            const int ql = i * 4 + g;
            f32x4 v = *(const f32x4*)&sc[w][ql * 68 + l15 * 4];
            *(f32x4*)&attn_h[(size_t)(qbase + ql) * 2048 + kt * 64 + l15 * 4] = v;
        }

        // PV (in-register, permuted Vt)
#pragma unroll
        for (int db = 0; db < 4; ++db) {
            oacc[0][db] = MFMA(pf0, vf[db * 2 + 0], oacc[0][db]);
            oacc[0][db] = MFMA(pf1, vf[db * 2 + 1], oacc[0][db]);
            oacc[1][db] = MFMA(pf2, vf[db * 2 + 0], oacc[1][db]);
            oacc[1][db] = MFMA(pf3, vf[db * 2 + 1], oacc[1][db]);
        }
    }

    // ctx write (each wave owns its rows; no reduction, no barrier)
#pragma unroll
    for (int mi = 0; mi < 2; ++mi) {
#pragma unroll
        for (int db = 0; db < 4; ++db) {
#pragma unroll
            for (int r = 0; r < 4; ++r) {
                int q = qt * 128 + qbase + mi * 16 + g4 + r;
                ctx[((size_t)(b * 2048 + q)) * 1024 + h * 64 + db * 16 + l15] =
                    f2bf(oacc[mi][db][r]);
            }
        }
    }
}

// ---------------- launcher ----------------
extern "C" void kernel_launch(void* const* d_in, const int* in_sizes, int n_in,
                              void* d_out, int out_size, void* d_ws, size_t ws_size,
                              hipStream_t stream) {
    const float* x  = (const float*)d_in[0];
    const float* wq = (const float*)d_in[1];
    const float* bq = (const float*)d_in[2];
    const float* wk = (const float*)d_in[3];
    const float* bk = (const float*)d_in[4];
    const float* wv = (const float*)d_in[5];
    const float* bv = (const float*)d_in[6];
    const float* wo = (const float*)d_in[7];
    const float* bo = (const float*)d_in[8];

    char* ws = (char*)d_ws;
    unsigned short* xb  = (unsigned short*)(ws);                    // [4096][1024] bf16
    unsigned short* wb  = (unsigned short*)(ws + 8388608);          // [4][1024][1024] bf16
    unsigned short* Qsc = (unsigned short*)(ws + 16777216);         // [32][2048][64] bf16 (scaled)
    unsigned short* Kb  = (unsigned short*)(ws + 25165824);         // [32][2048][64] bf16
    unsigned short* Vt  = (unsigned short*)(ws + 33554432);         // [32][64][2048] bf16 (k-permuted)
    unsigned short* ctx = (unsigned short*)(ws + 41943040);         // [4096][1024] bf16

    float* out  = (float*)d_out;
    float* attn = out + 4194304;

    convert_kernel<<<8192, 256, 0, stream>>>(x, wq, wk, wv, wo, xb, wb);
    gemm_kernel<<<dim3(24, 32), 256, 0, stream>>>(xb, wb, bq, bk, bv, 0,
                                                  Qsc, Kb, Vt, nullptr);
    attn_kernel<<<dim3(16, 32), 256, 0, stream>>>(Qsc, Kb, Vt, attn, ctx);
    gemm_kernel<<<dim3(8, 32), 256, 0, stream>>>(ctx, wb + 3 * 1048576, bo, bo, bo, 1,
                                                 nullptr, nullptr, nullptr, out);
}

// Round 17
// 332.611 us; speedup vs baseline: 1.4087x; 1.0113x over previous
//
#include <hip/hip_runtime.h>
#include <hip/hip_bf16.h>
#include <stdint.h>

// MultiHeadSelfAttention: B=2,H=16,S=2048,D=1024,DK=64. fp32 interface, bf16 MFMA internals.
// d_out = out[2,2048,1024] fp32 ++ attn[2,16,2048,2048] fp32.
//
// R17: TLP experiment. R10 attn math with QT=64, grid 32x32=1024 blocks ->
// 4 blocks/CU x 4 waves = 4 waves/SIMD (2x R10's TLP). No K/V reg prefetch
// (TLP hides latency; keeps VGPR <= 128 for launch_bounds(256,4)).
// Theory: HBM-store completion latency stalls waves via the finite VMEM queue;
// more resident waves = more outstanding stores = write stream saturates.

typedef __attribute__((ext_vector_type(4))) float f32x4;
typedef __attribute__((ext_vector_type(8))) short s16x8;
typedef __attribute__((ext_vector_type(4))) unsigned int u32x4;
typedef __attribute__((ext_vector_type(4))) unsigned short u16x4;

#define MFMA(a, b, c) __builtin_amdgcn_mfma_f32_16x16x32_bf16((a), (b), (c), 0, 0, 0)

#if __has_builtin(__builtin_amdgcn_exp2f)
#define EXP2(x) __builtin_amdgcn_exp2f(x)
#else
#define EXP2(x) exp2f(x)
#endif

__device__ __forceinline__ unsigned short f2bf(float f) {
    unsigned int u = __float_as_uint(f);
    unsigned int r = (u + 0x7FFFu + ((u >> 16) & 1u)) >> 16;
    return (unsigned short)r;
}
__device__ __forceinline__ unsigned int cvtpk_bf16(float lo, float hi) {
    unsigned int r;
    asm("v_cvt_pk_bf16_f32 %0, %1, %2" : "=v"(r) : "v"(lo), "v"(hi));
    return r;
}

// ---------------- Kernel 1: fp32 -> bf16 convert (x, wq, wk, wv, wo) ----------------
__global__ void convert_kernel(const float* __restrict__ x,
                               const float* __restrict__ wq, const float* __restrict__ wk,
                               const float* __restrict__ wv, const float* __restrict__ wo,
                               unsigned short* __restrict__ xb, unsigned short* __restrict__ wb) {
    size_t g = (size_t)blockIdx.x * blockDim.x + threadIdx.x;
    size_t i4 = g * 4;
    const float* src;
    unsigned short* dst;
    size_t off;
    if (i4 < 4194304) {            // x: 4096*1024
        src = x; dst = xb; off = i4;
    } else {
        size_t j = i4 - 4194304;
        int wsel = (int)(j >> 20); // each weight 1024*1024
        off = j & 1048575;
        src = (wsel == 0) ? wq : (wsel == 1) ? wk : (wsel == 2) ? wv : wo;
        dst = wb + ((size_t)wsel << 20);
    }
    float4 v = *(const float4*)(src + off);
    u16x4 o;
    o[0] = f2bf(v.x); o[1] = f2bf(v.y); o[2] = f2bf(v.z); o[3] = f2bf(v.w);
    *(u16x4*)(dst + off) = o;
}

// ---------------- Kernel 2/4: bt-GEMM, m97 structure (R10 epilogue) ----------------
// mode 0 epilogue: Qs (scaled), Kb ([bh][s][64]), Vt ([bh][d][s] with k-permuted cols).
__global__ __launch_bounds__(256, 3) void gemm_kernel(
    const unsigned short* __restrict__ A, const unsigned short* __restrict__ B,
    const float* __restrict__ bias_q, const float* __restrict__ bias_k,
    const float* __restrict__ bias_v, int mode,
    unsigned short* __restrict__ Qs, unsigned short* __restrict__ Kb,
    unsigned short* __restrict__ Vt, float* __restrict__ outp) {
    const int t = threadIdx.x;
    const int lane = t & 63;
    const int wv4 = t >> 6;            // wave 0..3
    const int wr = wv4 >> 1, wc = wv4 & 1;
    const int rowbase = blockIdx.y * 128;
    const int colbase = blockIdx.x * 128;

    __shared__ __align__(16) unsigned short lA[128 * 64];
    __shared__ __align__(16) unsigned short lB[128 * 64];

    const int crow = lane >> 3;        // 0..7
    const int ccol = (lane & 7) * 8;   // 0..56

    f32x4 acc[4][4];
#pragma unroll
    for (int mi = 0; mi < 4; ++mi)
#pragma unroll
        for (int ni = 0; ni < 4; ++ni)
            acc[mi][ni] = (f32x4){0.f, 0.f, 0.f, 0.f};

    const int l15 = lane & 15;
    const int koff = (lane >> 4) * 8;
    const int ar = wr * 64 + l15;
    const int br = wc * 64 + l15;

    for (int kt = 0; kt < 16; ++kt) {
        const int kbase = kt * 64 + ccol;
#pragma unroll
        for (int i = 0; i < 4; ++i) {
            const int c = wv4 * 4 + i;
            const int r = c * 8 + crow;
            __builtin_amdgcn_global_load_lds(
                (const __attribute__((address_space(1))) void*)(A + (size_t)(rowbase + r) * 1024 + kbase),
                (__attribute__((address_space(3))) void*)&lA[c * 512], 16, 0, 0);
            __builtin_amdgcn_global_load_lds(
                (const __attribute__((address_space(1))) void*)(B + (size_t)(colbase + r) * 1024 + kbase),
                (__attribute__((address_space(3))) void*)&lB[c * 512], 16, 0, 0);
        }
        __syncthreads();
#pragma unroll
        for (int kk = 0; kk < 2; ++kk) {
            s16x8 af[4], bf[4];
#pragma unroll
            for (int mi = 0; mi < 4; ++mi)
                af[mi] = *(const s16x8*)&lA[(ar + mi * 16) * 64 + kk * 32 + koff];
#pragma unroll
            for (int ni = 0; ni < 4; ++ni)
                bf[ni] = *(const s16x8*)&lB[(br + ni * 16) * 64 + kk * 32 + koff];
#pragma unroll
            for (int mi = 0; mi < 4; ++mi)
#pragma unroll
                for (int ni = 0; ni < 4; ++ni)
                    acc[mi][ni] = MFMA(af[mi], bf[ni], acc[mi][ni]);
        }
        __syncthreads();
    }

    if (mode == 1) {
#pragma unroll
        for (int ni = 0; ni < 4; ++ni) {
            int n = colbase + wc * 64 + ni * 16 + l15;
            float bv = bias_q[n];
#pragma unroll
            for (int mi = 0; mi < 4; ++mi) {
#pragma unroll
                for (int reg = 0; reg < 4; ++reg) {
                    int m = rowbase + wr * 64 + mi * 16 + (lane >> 4) * 4 + reg;
                    outp[(size_t)m * 1024 + n] = acc[mi][ni][reg] + bv;
                }
            }
        }
    } else {
        const int proj = colbase >> 10;
        const float* bias = (proj == 0) ? bias_q : (proj == 1) ? bias_k : bias_v;
        const float scale = (proj == 0) ? 0.18033688011112042f : 1.0f;  // 0.125*log2(e)
#pragma unroll
        for (int ni = 0; ni < 4; ++ni) {
            int n = colbase + wc * 64 + ni * 16 + l15;
            int nn = n & 1023;
            int h = nn >> 6, d = nn & 63;
            float bv = bias[nn];
#pragma unroll
            for (int mi = 0; mi < 4; ++mi) {
                int m0 = rowbase + wr * 64 + mi * 16 + (lane >> 4) * 4;
                int b = m0 >> 11, s0 = m0 & 2047;
                if (proj == 2) {
                    u16x4 pk;
#pragma unroll
                    for (int reg = 0; reg < 4; ++reg)
                        pk[reg] = f2bf(acc[mi][ni][reg] + bv);
                    // k-permuted column within each 32-block: p = 8g + 4ni + r
                    int j0 = s0 & 31;
                    int pg = (j0 >> 2) & 3, pn = (j0 >> 4) & 1;
                    int pcol = (s0 & ~31) | (pg << 3) | (pn << 2);
                    *(u16x4*)&Vt[((size_t)(b * 16 + h) * 64 + d) * 2048 + pcol] = pk;
                } else {
                    unsigned short* dstp = (proj == 0) ? Qs : Kb;
#pragma unroll
                    for (int reg = 0; reg < 4; ++reg)
                        dstp[((size_t)(b * 16 + h) * 2048 + (s0 + reg)) * 64 + d] =
                            f2bf((acc[mi][ni][reg] + bv) * scale);
                }
            }
        }
    }
}

// ---------------- Kernel 3: attention -- QT=64, 4 waves (wh x wc), 4 blocks/CU -------------
// wave w: wc = w&1 (k 32-slice), wh = w>>1 (q 32-half). Each wave: 32 q x 32 k per kt.
// No register prefetch (TLP hides load latency). 2 barriers total.
__global__ __launch_bounds__(256, 4) void attn_kernel(
    const unsigned short* __restrict__ Qs, const unsigned short* __restrict__ Kb,
    const unsigned short* __restrict__ Vt, float* __restrict__ attn,
    unsigned short* __restrict__ ctx) {
    const int t = threadIdx.x;
    const int lane = t & 63;
    const int l15 = lane & 15;
    const int g = lane >> 4;
    const int g4 = g * 4, g8 = g * 8;
    const int w = t >> 6;
    const int wc = w & 1, wh = w >> 1;
    const int qt = blockIdx.x;   // 0..31 (64-row tiles)
    const int bh = blockIdx.y;
    const int b = bh >> 4, h = bh & 15;

    const unsigned short* Qh = Qs + (size_t)bh * (2048 * 64);
    const unsigned short* Kh = Kb + (size_t)bh * (2048 * 64);
    const unsigned short* Vh = Vt + (size_t)bh * (64 * 2048);
    float* attn_h = attn + (size_t)bh * (2048 * 2048) + (size_t)(qt * 64) * 2048;

    __shared__ float lred[2][64];
    __shared__ float lO[2][32 * 68];

    const int qbase = wh * 32;

    // Q fragments (B-operand), mi in {0,1}
    s16x8 qf[4];
#pragma unroll
    for (int mi = 0; mi < 2; ++mi)
#pragma unroll
        for (int kk = 0; kk < 2; ++kk)
            qf[mi * 2 + kk] = *(const s16x8*)&Qh[(size_t)(qt * 64 + qbase + mi * 16 + l15) * 64 +
                                                kk * 32 + g8];

    // ---- PASS 1: denominators over wc's k-slice ----
    float qsum[2] = {0.f, 0.f};
    for (int kt = 0; kt < 32; ++kt) {
        s16x8 kf[4];
#pragma unroll
        for (int ni = 0; ni < 2; ++ni)
#pragma unroll
            for (int kk = 0; kk < 2; ++kk)
                kf[ni * 2 + kk] = *(const s16x8*)&Kh[(size_t)(kt * 64 + wc * 32 + ni * 16 + l15) *
                                                        64 + kk * 32 + g8];
        f32x4 sacc[2][2];
#pragma unroll
        for (int mi = 0; mi < 2; ++mi)
#pragma unroll
            for (int ni = 0; ni < 2; ++ni) sacc[mi][ni] = (f32x4){0.f, 0.f, 0.f, 0.f};
#pragma unroll
        for (int kk = 0; kk < 2; ++kk)
#pragma unroll
            for (int mi = 0; mi < 2; ++mi)
#pragma unroll
                for (int ni = 0; ni < 2; ++ni)
                    sacc[mi][ni] = MFMA(kf[ni * 2 + kk], qf[mi * 2 + kk], sacc[mi][ni]);
#pragma unroll
        for (int mi = 0; mi < 2; ++mi) {
            float e = 0.f;
#pragma unroll
            for (int ni = 0; ni < 2; ++ni)
#pragma unroll
                for (int r = 0; r < 4; ++r) e += EXP2(sacc[mi][ni][r]);
            qsum[mi] += e;
        }
    }
#pragma unroll
    for (int mi = 0; mi < 2; ++mi) {
        float v = qsum[mi];
        v += __shfl_xor(v, 16);
        v += __shfl_xor(v, 32);
        qsum[mi] = v;
    }
    if (lane < 16) {
#pragma unroll
        for (int mi = 0; mi < 2; ++mi)
            lred[wc][qbase + mi * 16 + lane] = qsum[mi];
    }
    __syncthreads();
    float rl[2];
#pragma unroll
    for (int mi = 0; mi < 2; ++mi) {
        int q = qbase + mi * 16 + l15;
        rl[mi] = 1.0f / (lred[0][q] + lred[1][q]);
    }

    // ---- PASS 2: QK -> exp -> attn stores -> pack P -> PV ----
    f32x4 oacc[2][4];
#pragma unroll
    for (int mi = 0; mi < 2; ++mi)
#pragma unroll
        for (int db = 0; db < 4; ++db) oacc[mi][db] = (f32x4){0.f, 0.f, 0.f, 0.f};

    for (int kt = 0; kt < 32; ++kt) {
        s16x8 kf[4];
#pragma unroll
        for (int ni = 0; ni < 2; ++ni)
#pragma unroll
            for (int kk = 0; kk < 2; ++kk)
                kf[ni * 2 + kk] = *(const s16x8*)&Kh[(size_t)(kt * 64 + wc * 32 + ni * 16 + l15) *
                                                        64 + kk * 32 + g8];
        s16x8 vf[4];
#pragma unroll
        for (int db = 0; db < 4; ++db)
            vf[db] = *(const s16x8*)&Vh[(size_t)(db * 16 + l15) * 2048 + kt * 64 + wc * 32 + g8];
        f32x4 sacc[2][2];
#pragma unroll
        for (int mi = 0; mi < 2; ++mi)
#pragma unroll
            for (int ni = 0; ni < 2; ++ni) sacc[mi][ni] = (f32x4){0.f, 0.f, 0.f, 0.f};
#pragma unroll
        for (int kk = 0; kk < 2; ++kk)
#pragma unroll
            for (int mi = 0; mi < 2; ++mi)
#pragma unroll
                for (int ni = 0; ni < 2; ++ni)
                    sacc[mi][ni] = MFMA(kf[ni * 2 + kk], qf[mi * 2 + kk], sacc[mi][ni]);

        s16x8 pf[2];
#pragma unroll
        for (int mi = 0; mi < 2; ++mi) {
            const int q = qbase + mi * 16 + l15;
            float p[8];
#pragma unroll
            for (int ni = 0; ni < 2; ++ni) {
                p[ni * 4 + 0] = EXP2(sacc[mi][ni][0]) * rl[mi];
                p[ni * 4 + 1] = EXP2(sacc[mi][ni][1]) * rl[mi];
                p[ni * 4 + 2] = EXP2(sacc[mi][ni][2]) * rl[mi];
                p[ni * 4 + 3] = EXP2(sacc[mi][ni][3]) * rl[mi];
                f32x4 pv = {p[ni * 4 + 0], p[ni * 4 + 1], p[ni * 4 + 2], p[ni * 4 + 3]};
                *(f32x4*)&attn_h[(size_t)q * 2048 + kt * 64 + wc * 32 + ni * 16 + g4] = pv;
            }
            u32x4 pkw;
            pkw[0] = cvtpk_bf16(p[0], p[1]);
            pkw[1] = cvtpk_bf16(p[2], p[3]);
            pkw[2] = cvtpk_bf16(p[4], p[5]);
            pkw[3] = cvtpk_bf16(p[6], p[7]);
            pf[mi] = *(const s16x8*)&pkw;
        }
#pragma unroll
        for (int mi = 0; mi < 2; ++mi)
#pragma unroll
            for (int db = 0; db < 4; ++db)
                oacc[mi][db] = MFMA(pf[mi], vf[db], oacc[mi][db]);
    }

    // ---- cross-wc O reduction + ctx write ----
    if (wc == 1) {
#pragma unroll
        for (int mi = 0; mi < 2; ++mi)
#pragma unroll
            for (int db = 0; db < 4; ++db)
#pragma unroll
                for (int r = 0; r < 4; ++r)
                    lO[wh][(mi * 16 + g4 + r) * 68 + db * 16 + l15] = oacc[mi][db][r];
    }
    __syncthreads();
    if (wc == 0) {
#pragma unroll
        for (int mi = 0; mi < 2; ++mi) {
#pragma unroll
            for (int db = 0; db < 4; ++db) {
#pragma unroll
                for (int r = 0; r < 4; ++r) {
                    float s = oacc[mi][db][r] + lO[wh][(mi * 16 + g4 + r) * 68 + db * 16 + l15];
                    int q = qt * 64 + qbase + mi * 16 + g4 + r;
                    ctx[((size_t)(b * 2048 + q)) * 1024 + h * 64 + db * 16 + l15] = f2bf(s);
                }
            }
        }
    }
}

// ---------------- launcher ----------------
extern "C" void kernel_launch(void* const* d_in, const int* in_sizes, int n_in,
                              void* d_out, int out_size, void* d_ws, size_t ws_size,
                              hipStream_t stream) {
    const float* x  = (const float*)d_in[0];
    const float* wq = (const float*)d_in[1];
    const float* bq = (const float*)d_in[2];
    const float* wk = (const float*)d_in[3];
    const float* bk = (const float*)d_in[4];
    const float* wv = (const float*)d_in[5];
    const float* bv = (const float*)d_in[6];
    const float* wo = (const float*)d_in[7];
    const float* bo = (const float*)d_in[8];

    char* ws = (char*)d_ws;
    unsigned short* xb  = (unsigned short*)(ws);                    // [4096][1024] bf16
    unsigned short* wb  = (unsigned short*)(ws + 8388608);          // [4][1024][1024] bf16
    unsigned short* Qsc = (unsigned short*)(ws + 16777216);         // [32][2048][64] bf16 (scaled)
    unsigned short* Kb  = (unsigned short*)(ws + 25165824);         // [32][2048][64] bf16
    unsigned short* Vt  = (unsigned short*)(ws + 33554432);         // [32][64][2048] bf16 (k-permuted)
    unsigned short* ctx = (unsigned short*)(ws + 41943040);         // [4096][1024] bf16

    float* out  = (float*)d_out;
    float* attn = out + 4194304;

    convert_kernel<<<8192, 256, 0, stream>>>(x, wq, wk, wv, wo, xb, wb);
    gemm_kernel<<<dim3(24, 32), 256, 0, stream>>>(xb, wb, bq, bk, bv, 0,
                                                  Qsc, Kb, Vt, nullptr);
    attn_kernel<<<dim3(32, 32), 256, 0, stream>>>(Qsc, Kb, Vt, attn, ctx);
    gemm_kernel<<<dim3(8, 32), 256, 0, stream>>>(ctx, wb + 3 * 1048576, bo, bo, bo, 1,
                                                 nullptr, nullptr, nullptr, out);
}